// Round 5
// baseline (340.192 us; speedup 1.0000x reference)
//
#include <hip/hip_runtime.h>
#include <hip/hip_bf16.h>

// Problem constants (B,T,H fixed by setup_inputs)
#define B_ 16
#define T_ 8192
#define H_ 256
#define M_ (B_ * T_)   // 131072 rows
#define STRIDE_ 8      // window over [max(0,t-8), t], count = min(t+1, 9)

typedef __bf16 bf16x8 __attribute__((ext_vector_type(8)));
typedef float f32x4 __attribute__((ext_vector_type(4)));

// round-to-nearest-even fp32 -> bf16 bits
__device__ __forceinline__ unsigned short f2bf(float f) {
  unsigned u = __builtin_bit_cast(unsigned, f);
  u += 0x7fffu + ((u >> 16) & 1u);
  return (unsigned short)(u >> 16);
}

// ---------------------------------------------------------------------------
// Kernel 1: Wpk[ks][n][kk] = bf16(Wcat[n][ks*32+kk]), ks<16, n<256, kk<32
//   Wcat[n][k] = k<256 ? W_lin[n][k] : W_mem[n][k-256]
// A wave's b-frag load (16 rows x 32 elems) is one contiguous 1 KB segment.
// Also bias[o] = b_lin[o]+b_mem[o].
// ---------------------------------------------------------------------------
__global__ __launch_bounds__(256) void wcat_kernel(
    const float* __restrict__ Wl, const float* __restrict__ bl,
    const float* __restrict__ Wm, const float* __restrict__ bm,
    unsigned short* __restrict__ Wpk, float* __restrict__ bias) {
  const int e = blockIdx.x * 256 + threadIdx.x;
  const int ks = e >> 13;
  const int n = (e >> 5) & 255;
  const int kk = e & 31;
  const int k = ks * 32 + kk;
  const float w = (k < 256) ? Wl[n * 256 + k] : Wm[n * 256 + (k - 256)];
  Wpk[e] = f2bf(w);
  if (e < 256) bias[e] = bl[e] + bm[e];
}

// ---------------------------------------------------------------------------
// Kernel 2 (fused, persistent): out[M,256] = [x | winmean(x)] @ Wcat^T + bias
// 256 blocks x 512 threads (8 waves). Wave w owns output cols [w*32, w*32+32):
// its ENTIRE B operand (32 cols x K=512) lives in 128 VGPRs, loaded ONCE.
// Block processes 8 M-tiles of 64 rows. Per tile: 8 K-iterations of 64
// (32 x-cols + their 32 mean-cols from ONE x read), A staged via XOR-swizzled
// double-buffered LDS (one lgkm-only barrier per iter — no vmcnt drain).
// x for the next step is register-prefetched during the MFMA phase.
// ---------------------------------------------------------------------------
__global__ __launch_bounds__(512, 2) void fused_kernel(
    const float* __restrict__ x,            // [M, 256] fp32
    const unsigned short* __restrict__ Wpk, // [16][256][32] bf16 bits
    const float* __restrict__ bias,         // [256]
    float* __restrict__ out) {              // [M, 256] fp32
  __shared__ __align__(16) unsigned short As[2][64 * 64];  // 16 KB total
  const int tid = threadIdx.x;
  const int bid = blockIdx.x;      // 0..255, tiles bid*8 .. bid*8+7
  const int w = tid >> 6;
  const int l = tid & 63;
  const int wc = w << 5;           // wave's 32-col slice
  const int lm = l & 15;
  const int kc4 = l >> 4;          // 16B chunk index (0..3)
  const int kq = kc4 << 3;

  // A staging: col-pair p (16 float2 pairs), row-group g (32 groups x 2 rows)
  const int p = tid & 15, g = tid >> 4;
  const float2* __restrict__ x2 = (const float2*)x;

  // --- B: whole per-wave W slice in registers, loaded once ---
  bf16x8 breg[16][2];
#pragma unroll
  for (int ks = 0; ks < 16; ++ks)
#pragma unroll
    for (int j = 0; j < 2; ++j)
      breg[ks][j] =
          *(const bf16x8*)&Wpk[(((ks << 8) + wc + (j << 4) + lm) << 5) + kq];

  // bias for this wave's two col-frags
  float bsv[2];
#pragma unroll
  for (int j = 0; j < 2; ++j) bsv[j] = bias[wc + (j << 4) + lm];

  // --- prologue: x chunk for (tile 0, it 0); 8-row halo above each group ---
  float2 v[10];
  {
    const int m0 = bid << 9;
    const int tb0 = m0 & (T_ - 1);
#pragma unroll
    for (int i = 0; i < 10; ++i) {
      const int rl = (g << 1) - 8 + i;
      float2 val = {0.f, 0.f};
      if (tb0 + rl >= 0) val = x2[(size_t)(m0 + rl) * 128 + p];
      v[i] = val;
    }
  }

  for (int tile = 0; tile < 8; ++tile) {
    const int m0 = ((bid << 3) + tile) << 6;
    const int tb0 = m0 & (T_ - 1);

    f32x4 acc[4][2];
#pragma unroll
    for (int i = 0; i < 4; ++i)
#pragma unroll
      for (int j = 0; j < 2; ++j) acc[i][j] = (f32x4){0.f, 0.f, 0.f, 0.f};

#pragma unroll
    for (int it = 0; it < 8; ++it) {
      const int cur = it & 1;
      unsigned* __restrict__ As32 = (unsigned*)As[cur];

      // --- means (running 9-row window) + swizzled ds_write ---
      float sx = 0.f, sy = 0.f;
#pragma unroll
      for (int i = 0; i < 8; ++i) { sx += v[i].x; sy += v[i].y; }
#pragma unroll
      for (int rr = 0; rr < 2; ++rr) {
        sx += v[rr + 8].x; sy += v[rr + 8].y;
        const int r = (g << 1) + rr;
        const int t = tb0 + r;
        const float inv =
            (t >= STRIDE_) ? (1.f / 9.f) : __builtin_amdgcn_rcpf((float)(t + 1));
        const unsigned xp =
            (unsigned)f2bf(v[rr + 8].x) | ((unsigned)f2bf(v[rr + 8].y) << 16);
        const unsigned mp =
            (unsigned)f2bf(sx * inv) | ((unsigned)f2bf(sy * inv) << 16);
        const int sw = r & 7;
        As32[r * 32 + (((p >> 2) ^ sw) << 2) + (p & 3)] = xp;        // chunks 0-3
        As32[r * 32 + (((4 + (p >> 2)) ^ sw) << 2) + (p & 3)] = mp;  // chunks 4-7
        sx -= v[rr].x; sy -= v[rr].y;
      }
      __syncthreads();  // lgkm-only drain: As[cur] visible; x loads unaffected

      // --- A frags: swizzled ds_read_b128 (x half + mean half) ---
      bf16x8 a0[4], a1[4];
#pragma unroll
      for (int i = 0; i < 4; ++i) {
        const int R = (i << 4) + lm;
        a0[i] = *(const bf16x8*)&As[cur][R * 64 + ((kc4 ^ (R & 7)) << 3)];
        a1[i] = *(const bf16x8*)&As[cur][R * 64 + (((4 + kc4) ^ (R & 7)) << 3)];
      }

      // --- prefetch next step's x (rides through barriers; consumed next it)
      if (it < 7 || tile < 7) {
        const int nit = (it < 7) ? it + 1 : 0;
        const int nm0 = (it < 7) ? m0 : m0 + 64;
        const int ntb0 = nm0 & (T_ - 1);
#pragma unroll
        for (int i = 0; i < 10; ++i) {
          const int rl = (g << 1) - 8 + i;
          float2 val = {0.f, 0.f};
          if (ntb0 + rl >= 0)
            val = x2[(size_t)(nm0 + rl) * 128 + (nit << 4) + p];
          v[i] = val;
        }
      }

      // --- MFMA: k-steps it (x part) and it+8 (mean part) ---
#pragma unroll
      for (int i = 0; i < 4; ++i)
#pragma unroll
        for (int j = 0; j < 2; ++j)
          acc[i][j] = __builtin_amdgcn_mfma_f32_16x16x32_bf16(
              a0[i], breg[it][j], acc[i][j], 0, 0, 0);
#pragma unroll
      for (int i = 0; i < 4; ++i)
#pragma unroll
        for (int j = 0; j < 2; ++j)
          acc[i][j] = __builtin_amdgcn_mfma_f32_16x16x32_bf16(
              a1[i], breg[it + 8][j], acc[i][j], 0, 0, 0);
    }

    // --- epilogue: C/D layout col = l&15, row = (l>>4)*4 + reg ---
    const int r0 = (l >> 4) << 2;
#pragma unroll
    for (int j = 0; j < 2; ++j) {
      const int o = wc + (j << 4) + lm;
      const float bs = bsv[j];
#pragma unroll
      for (int i = 0; i < 4; ++i) {
        const size_t mr = (size_t)(m0 + (i << 4) + r0);
#pragma unroll
        for (int r = 0; r < 4; ++r) out[(mr + r) * 256 + o] = acc[i][j][r] + bs;
      }
    }
  }
}

// ---------------------------------------------------------------------------
extern "C" void kernel_launch(void* const* d_in, const int* in_sizes, int n_in,
                              void* d_out, int out_size, void* d_ws, size_t ws_size,
                              hipStream_t stream) {
  const float* x  = (const float*)d_in[0];
  const float* Wl = (const float*)d_in[1];
  const float* bl = (const float*)d_in[2];
  const float* Wm = (const float*)d_in[3];
  const float* bm = (const float*)d_in[4];
  float* out = (float*)d_out;

  // workspace: Wpk 16x256x32 bf16 (256 KiB) + bias 256 f32 (1 KiB)
  char* ws = (char*)d_ws;
  unsigned short* Wpk = (unsigned short*)ws;
  float* bias = (float*)(ws + (size_t)16 * 256 * 32 * 2);

  wcat_kernel<<<512, 256, 0, stream>>>(Wl, bl, Wm, bm, Wpk, bias);
  fused_kernel<<<256, 512, 0, stream>>>(x, Wpk, bias, out);
}